// Round 15
// baseline (1014.239 us; speedup 1.0000x reference)
//
#include <hip/hip_runtime.h>
#include <math.h>

#define BB 32
#define TT 512
#define IND 2048
#define DD 512
#define OD 29
#define WCOLS 64   // Wt cols
#define GC 32      // GPC cols (G + C)
#define PTK 116    // Ptg chunk stride: 29 k's * 4 floats
#define PTB 18560  // Ptg per-batch floats: 160 chunks * 116

typedef float v2f __attribute__((ext_vector_type(2)));

__device__ __forceinline__ v2f pk_fma(v2f a, v2f b, v2f c) {
  v2f d;
  asm("v_pk_fma_f32 %0, %1, %2, %3" : "=v"(d) : "v"(a), "v"(b), "v"(c));
  return d;
}

template<int CTRL, int RM>
__device__ __forceinline__ float updpp(float idv, float x) {
  return __int_as_float(__builtin_amdgcn_update_dpp(
      __float_as_int(idv), __float_as_int(x), CTRL, RM, 0xf, false));
}

// All-VALU wave64 reductions (DPP ladder), broadcast via readlane 63.
__device__ __forceinline__ float red_max64(float x) {
  const float ID = -3.0e38f;
  x = fmaxf(x, updpp<0xB1, 0xf>(ID, x));
  x = fmaxf(x, updpp<0x4E, 0xf>(ID, x));
  x = fmaxf(x, updpp<0x124, 0xf>(ID, x));
  x = fmaxf(x, updpp<0x128, 0xf>(ID, x));
  x = fmaxf(x, updpp<0x142, 0xa>(ID, x));
  x = fmaxf(x, updpp<0x143, 0xc>(ID, x));
  return __int_as_float(__builtin_amdgcn_readlane(__float_as_int(x), 63));
}

__device__ __forceinline__ float red_sum64(float x) {
  x += updpp<0xB1, 0xf>(0.f, x);
  x += updpp<0x4E, 0xf>(0.f, x);
  x += updpp<0x124, 0xf>(0.f, x);
  x += updpp<0x128, 0xf>(0.f, x);
  x += updpp<0x142, 0xa>(0.f, x);
  x += updpp<0x143, 0xc>(0.f, x);
  return __int_as_float(__builtin_amdgcn_readlane(__float_as_int(x), 63));
}

// ---------------- zero-fill ----------------
__global__ void k_zero(float* __restrict__ p, int n) {
  int n4 = n >> 2;
  int i = blockIdx.x * blockDim.x + threadIdx.x;
  int stride = gridDim.x * blockDim.x;
  float4 z = make_float4(0.f, 0.f, 0.f, 0.f);
  for (int j = i; j < n4; j += stride) ((float4*)p)[j] = z;
  int base = (n4 << 2) + i;
  if (base < n) p[base] = 0.f;
}

// ---------------- fold weights: Wt[2049][64] ----------------
// cols 0..28: scale*W_in@W_q^T (G); col 29: scale*W_in@b_q (C);
// cols 32..60: W_in@W_out (P); row 2048 = bias row (b_in version).
__global__ __launch_bounds__(64) void k_transform(
    const float* __restrict__ W_in, const float* __restrict__ b_in,
    const float* __restrict__ W_q,  const float* __restrict__ b_q,
    const float* __restrict__ W_out, float* __restrict__ Wt) {
  int i = blockIdx.x;          // 0..2048
  int c = threadIdx.x;         // 0..63
  const float* row = (i < IND) ? (W_in + (size_t)i * DD) : b_in;
  const float* m;
  int strd;
  bool valid = true, dscale = false;
  if (c < OD)                { m = W_q + (size_t)c * DD; strd = 1; dscale = true; }
  else if (c == OD)          { m = b_q;                  strd = 1; dscale = true; }
  else if (c >= 32 && c < 32 + OD) { m = W_out + (c - 32); strd = OD; }
  else                       { m = b_q; strd = 0; valid = false; }
  float a0 = 0.f, a1 = 0.f, a2 = 0.f, a3 = 0.f;
  for (int d = 0; d < DD; d += 4) {
    a0 += row[d + 0] * m[(size_t)(d + 0) * strd];
    a1 += row[d + 1] * m[(size_t)(d + 1) * strd];
    a2 += row[d + 2] * m[(size_t)(d + 2) * strd];
    a3 += row[d + 3] * m[(size_t)(d + 3) * strd];
  }
  float acc = (a0 + a1) + (a2 + a3);
  if (dscale) acc *= (1.0f / sqrtf((float)DD));
  if (!valid) acc = 0.f;
  Wt[(size_t)i * WCOLS + c] = acc;
}

// -- GEMM: GPC (G+C, 32 cols) + Ptg (P, chunked [j/4][k][j%4] layout) --
__global__ __launch_bounds__(256) void k_gemm(
    const float* __restrict__ x, const float* __restrict__ Wt,
    float* __restrict__ GPC, float* __restrict__ Ptg) {
  __shared__ float xt[128][65];
  int tid = threadIdx.x;
  int r = tid & 63;
  int cg16 = __builtin_amdgcn_readfirstlane((tid >> 6) << 4);
  int m0 = blockIdx.x << 6;
  int lr = tid >> 2, lc = tid & 3;
  const float* xl = x + (size_t)(m0 + lr) * IND;
  float4 a0 = make_float4(0,0,0,0), a1 = a0, a2 = a0, a3 = a0;
  for (int kk = 0; kk < IND; kk += 128) {
    __syncthreads();
    #pragma unroll
    for (int j = 0; j < 8; ++j) {
      int k = (lc + 4 * j) << 2;
      float4 v = *(const float4*)(xl + kk + k);
      xt[k + 0][lr] = v.x; xt[k + 1][lr] = v.y;
      xt[k + 2][lr] = v.z; xt[k + 3][lr] = v.w;
    }
    __syncthreads();
    const float* wb = Wt + (size_t)kk * WCOLS + cg16;
    #pragma unroll 4
    for (int k = 0; k < 128; ++k) {
      float xv = xt[k][r];
      const float* wk = wb + (size_t)k * WCOLS;
      float4 w0 = *(const float4*)(wk + 0);
      float4 w1 = *(const float4*)(wk + 4);
      float4 w2 = *(const float4*)(wk + 8);
      float4 w3 = *(const float4*)(wk + 12);
      a0.x += xv * w0.x; a0.y += xv * w0.y; a0.z += xv * w0.z; a0.w += xv * w0.w;
      a1.x += xv * w1.x; a1.y += xv * w1.y; a1.z += xv * w1.z; a1.w += xv * w1.w;
      a2.x += xv * w2.x; a2.y += xv * w2.y; a2.z += xv * w2.z; a2.w += xv * w2.w;
      a3.x += xv * w3.x; a3.y += xv * w3.y; a3.z += xv * w3.z; a3.w += xv * w3.w;
    }
  }
  const float* br = Wt + (size_t)IND * WCOLS + cg16;
  float4 b0 = *(const float4*)(br + 0), b1 = *(const float4*)(br + 4);
  float4 b2 = *(const float4*)(br + 8), b3 = *(const float4*)(br + 12);
  a0.x += b0.x; a0.y += b0.y; a0.z += b0.z; a0.w += b0.w;
  a1.x += b1.x; a1.y += b1.y; a1.z += b1.z; a1.w += b1.w;
  a2.x += b2.x; a2.y += b2.y; a2.z += b2.z; a2.w += b2.w;
  a3.x += b3.x; a3.y += b3.y; a3.z += b3.z; a3.w += b3.w;
  if (cg16 < 32) {
    float* o = GPC + (size_t)(m0 + r) * GC + cg16;
    *(float4*)(o + 0) = a0; *(float4*)(o + 4) = a1;
    *(float4*)(o + 8) = a2; *(float4*)(o + 12) = a3;
  } else {
    int bb = m0 >> 9;               // batch
    int jj = (m0 & 511) + r;        // row within batch
    int c0 = cg16 - 32;             // 0 or 16
    float va[16] = {a0.x,a0.y,a0.z,a0.w, a1.x,a1.y,a1.z,a1.w,
                    a2.x,a2.y,a2.z,a2.w, a3.x,a3.y,a3.z,a3.w};
    float* pb = Ptg + (size_t)bb * PTB + (size_t)(jj >> 2) * PTK + (jj & 3);
    #pragma unroll
    for (int cc = 0; cc < 16; ++cc)
      if (c0 + cc < OD) pb[(size_t)(c0 + cc) * 4] = va[cc];
  }
}

// ---------------- scan helpers ----------------
__device__ __forceinline__ void ld_g(v2f* g, const float* gb, int j) {
  const float4* s = (const float4*)(gb + (size_t)j * GC);
  #pragma unroll
  for (int u = 0; u < 8; ++u) {
    float4 v = s[u];
    g[2*u+0] = (v2f){v.x, v.y};
    g[2*u+1] = (v2f){v.z, v.w};
  }
}

// pairs 0..14 cover cols 0..29 (col 29 = C, paired against q-slot 1.0)
__device__ __forceinline__ float score_pk(const v2f* g, const v2f* qp) {
  v2f a0 = pk_fma(qp[0], g[0], (v2f){0.f, 0.f});
  v2f a1 = pk_fma(qp[1], g[1], (v2f){0.f, 0.f});
  v2f a2 = pk_fma(qp[2], g[2], (v2f){0.f, 0.f});
  #pragma unroll
  for (int i = 3; i < 15; i += 3) {
    a0 = pk_fma(qp[i+0], g[i+0], a0);
    a1 = pk_fma(qp[i+1], g[i+1], a1);
    a2 = pk_fma(qp[i+2], g[i+2], a2);
  }
  v2f s = a0 + a1;
  s = s + a2;
  return s.x + s.y;
}

// ---- scan: 8 waves/block (2/SIMD), 1 batch/wave, R12 internals ----
__global__ __launch_bounds__(512, 2) void k_scan(
    const float* __restrict__ GPC, const float* __restrict__ Ptg,
    const int* __restrict__ lens_raw,
    const float* __restrict__ b_out, const int* __restrict__ wsp,
    float* __restrict__ outputs, float* __restrict__ weights) {
  __shared__ __align__(16) float w_all[8][640];   // per-wave e-buffer (20 KB)

  int wvu = __builtin_amdgcn_readfirstlane((int)(threadIdx.x >> 6));
  int l   = threadIdx.x & 63;
  int b   = blockIdx.x * 8 + wvu;
  float* w_lds = w_all[wvu];

  int len;
  { // int32 / int64 hedge: lens sorted desc, all >0, so word[1]==0 <=> int64
    int probe = lens_raw[1];
    len = (probe == 0) ? lens_raw[2 * b] : lens_raw[b];
  }
  if (len > TT) len = TT;
  if (len < 0) len = 0;
  int ws = wsp[0];

  const float* gb = GPC + (size_t)b * TT * GC;
  for (int j = l; j < 640; j += 64) w_lds[j] = 0.f;   // own slice, no barrier

  int k = l & 31, h = l >> 5;
  int kc = (k < OD) ? k : (OD - 1);          // lanes 29..31 mirror row 28
  const float* pvK = Ptg + (size_t)b * PTB + kc * 4;
  float boutk = (k < OD) ? b_out[k] : 0.f;

  float* outb = outputs + (size_t)b * TT * OD;
  float* wb   = weights + (size_t)b * TT * TT;

  // query as packed uniform pairs; init 'fix': ones, last channel = 9
  v2f qp[15];
  #pragma unroll
  for (int i = 0; i < 14; ++i) qp[i] = (v2f){1.f, 1.f};
  qp[14] = (v2f){9.f, 1.f};

  // rolling 192-row G register file: row j -> lane j%64, slot (j>>6)%3
  v2f g0[16], g1[16], g2[16];
  int j0r = l, j1r = 64 + l, j2r = 128 + l;
  ld_g(g0, gb, j0r); ld_g(g1, gb, j1r); ld_g(g2, gb, j2r);

  int jlo = 0;
  int jhi = (ws < len - 1) ? ws : (len - 1);

  float m_run = -3.0e38f;   // deferred running max
  int t = 0;
  for (; t < len; ++t) {
    int qb = jlo >> 2;                       // 4-row chunk index
    // ---- Ptg reads (VMEM; sibling wave covers the wait) ----
    float4 rp[17];
    {
      const float* pr = pvK + (size_t)(qb + h) * PTK;
      #pragma unroll
      for (int i = 0; i < 17; ++i) rp[i] = *(const float4*)(pr + (size_t)(2 * i) * PTK);
    }
    __builtin_amdgcn_sched_barrier(0);
    // ---- scores from register slots (packed f32 FMA, q uniform) ----
    float s0 = score_pk(g0, qp);
    float s1 = score_pk(g1, qp);
    float s2 = score_pk(g2, qp);
    bool v0 = (j0r >= jlo) & (j0r <= jhi);
    bool v1 = (j1r >= jlo) & (j1r <= jhi);
    bool v2 = (j2r >= jlo) & (j2r <= jhi);
    const float NEG = -3.0e38f;
    float mx0 = fmaxf(fmaxf(v0 ? s0 : NEG, v1 ? s1 : NEG), v2 ? s2 : NEG);
    // speculative exp with running max; rare fixup when band violated
    float mx = m_run;
    float e0 = v0 ? __expf(s0 - mx) : 0.f;
    float e1 = v1 ? __expf(s1 - mx) : 0.f;
    float e2 = v2 ? __expf(s2 - mx) : 0.f;
    if (!(__all(mx0 <= m_run + 8.0f) && __any(mx0 >= m_run - 20.0f))) {
      mx = red_max64(mx0);
      m_run = mx;
      e0 = v0 ? __expf(s0 - mx) : 0.f;
      e1 = v1 ? __expf(s1 - mx) : 0.f;
      e2 = v2 ? __expf(s2 - mx) : 0.f;
    }
    // unnormalized e scatter into LDS (row j%64 == lane: conflict-free)
    if (l == 0 && jlo > 0) w_lds[jlo - 1] = 0.f;  // evict stale window entry
    if (v0) w_lds[j0r] = e0;
    if (v1) w_lds[j1r] = e1;
    if (v2) w_lds[j2r] = e2;
    // sum reduce + rcp + weight stores: cover for the w-read drain below
    float sm = red_sum64(e0 + e1 + e2);
    float invS = __builtin_amdgcn_rcpf(sm);
    float* wrow = wb + (size_t)t * TT;
    if (v0) wrow[j0r] = e0 * invS;
    if (v1) wrow[j1r] = e1 * invS;
    if (v2) wrow[j2r] = e2 * invS;
    // ---- PV: w from LDS (in-order after e-writes), P from rp registers ----
    v2f pA = (v2f){0.f, 0.f}, pB = (v2f){0.f, 0.f};
    v2f pC = (v2f){0.f, 0.f}, pD = (v2f){0.f, 0.f};
    {
      const float* wr = w_lds + ((qb + h) << 2);
      #pragma unroll
      for (int i = 0; i < 17; i += 2) {
        float4 wv = *(const float4*)(wr + (i << 3));
        pA = pk_fma((v2f){wv.x, wv.y}, (v2f){rp[i].x, rp[i].y}, pA);
        pB = pk_fma((v2f){wv.z, wv.w}, (v2f){rp[i].z, rp[i].w}, pB);
      }
      #pragma unroll
      for (int i = 1; i < 17; i += 2) {
        float4 wv = *(const float4*)(wr + (i << 3));
        pC = pk_fma((v2f){wv.x, wv.y}, (v2f){rp[i].x, rp[i].y}, pC);
        pD = pk_fma((v2f){wv.z, wv.w}, (v2f){rp[i].z, rp[i].w}, pD);
      }
    }
    v2f ps = (pA + pC) + (pB + pD);
    float tot = ps.x + ps.y;
    // cross-half combine: pure-VALU permlane32_swap (proven R8/R10/R12)
    float tc = tot;
    asm("v_permlane32_swap_b32 %0, %1" : "+v"(tot), "+v"(tc));
    float comb = tot + tc;
    float nq = comb * invS + boutk;
    if (h == 0 && k < OD) outb[(size_t)t * OD + k] = nq;
    // broadcast new query into packed uniform pairs (on-chain)
    #pragma unroll
    for (int kk = 0; kk < 14; ++kk) {
      float lo = __int_as_float(__builtin_amdgcn_readlane(__float_as_int(nq), 2*kk));
      float hi = __int_as_float(__builtin_amdgcn_readlane(__float_as_int(nq), 2*kk+1));
      qp[kk] = (v2f){lo, hi};
    }
    qp[14] = (v2f){__int_as_float(__builtin_amdgcn_readlane(__float_as_int(nq), 28)), 1.0f};
    // rolling refill, prefetch distance 2 (fully off-chain)
    int jnew = t + 2 + ws;
    if (jnew >= 192 && jnew < TT) {
      int sl = (jnew >> 6) % 3;
      int ln = jnew & 63;
      if (sl == 0)      { if (l == ln) { ld_g(g0, gb, jnew); j0r = jnew; } }
      else if (sl == 1) { if (l == ln) { ld_g(g1, gb, jnew); j1r = jnew; } }
      else              { if (l == ln) { ld_g(g2, gb, jnew); j2r = jnew; } }
    }
    // advance window
    jlo = (t + 1) - ws; if (jlo < 0) jlo = 0;
    jhi = (t + 1) + ws; if (jhi > len - 1) jhi = len - 1;
  }
  // dead tail: outputs = b_out, weights stay zero
  for (; t < TT; ++t)
    if (l < OD) outb[(size_t)t * OD + l] = boutk;
}

extern "C" void kernel_launch(void* const* d_in, const int* in_sizes, int n_in,
                              void* d_out, int out_size, void* d_ws, size_t ws_size,
                              hipStream_t stream) {
  const float* x     = (const float*)d_in[0];
  const int*   lens  = (const int*)d_in[1];
  const float* W_in  = (const float*)d_in[2];
  const float* b_in  = (const float*)d_in[3];
  const float* W_q   = (const float*)d_in[4];
  const float* b_q   = (const float*)d_in[5];
  const float* W_out = (const float*)d_in[6];
  const float* b_out = (const float*)d_in[7];
  const int*   wsp   = (const int*)d_in[8];
  float* out = (float*)d_out;

  float* Wt  = (float*)d_ws;                      // [2049][64]
  float* GPC = Wt + (size_t)(IND + 1) * WCOLS;    // [B*T][32]
  float* Ptg = GPC + (size_t)BB * TT * GC;        // [B][160][29][4]

  k_zero<<<1024, 256, 0, stream>>>(out, out_size);
  k_zero<<<512, 256, 0, stream>>>(Ptg, BB * PTB);
  k_transform<<<IND + 1, 64, 0, stream>>>(W_in, b_in, W_q, b_q, W_out, Wt);
  k_gemm<<<(BB * TT) / 64, 256, 0, stream>>>(x, Wt, GPC, Ptg);

  float* outputs = out;
  float* weights = out + (size_t)BB * TT * OD;
  k_scan<<<BB / 8, 512, 0, stream>>>(GPC, Ptg, lens, b_out, wsp, outputs, weights);
}

// Round 16
// 865.415 us; speedup vs baseline: 1.1720x; 1.1720x over previous
//
#include <hip/hip_runtime.h>
#include <math.h>

#define BB 32
#define TT 512
#define IND 2048
#define DD 512
#define OD 29
#define WCOLS 64   // Wt cols
#define GC 32      // GPC cols (G + C)
#define PTK 116    // Ptg chunk stride: 29 k's * 4 floats
#define PTB 18560  // Ptg per-batch floats: 160 chunks * 116

typedef float v2f __attribute__((ext_vector_type(2)));

__device__ __forceinline__ v2f pk_fma(v2f a, v2f b, v2f c) {
  v2f d;
  asm("v_pk_fma_f32 %0, %1, %2, %3" : "=v"(d) : "v"(a), "v"(b), "v"(c));
  return d;
}

template<int CTRL, int RM>
__device__ __forceinline__ float updpp(float idv, float x) {
  return __int_as_float(__builtin_amdgcn_update_dpp(
      __float_as_int(idv), __float_as_int(x), CTRL, RM, 0xf, false));
}

// All-VALU wave64 reductions (DPP ladder), broadcast via readlane 63.
__device__ __forceinline__ float red_max64(float x) {
  const float ID = -3.0e38f;
  x = fmaxf(x, updpp<0xB1, 0xf>(ID, x));
  x = fmaxf(x, updpp<0x4E, 0xf>(ID, x));
  x = fmaxf(x, updpp<0x124, 0xf>(ID, x));
  x = fmaxf(x, updpp<0x128, 0xf>(ID, x));
  x = fmaxf(x, updpp<0x142, 0xa>(ID, x));
  x = fmaxf(x, updpp<0x143, 0xc>(ID, x));
  return __int_as_float(__builtin_amdgcn_readlane(__float_as_int(x), 63));
}

__device__ __forceinline__ float red_sum64(float x) {
  x += updpp<0xB1, 0xf>(0.f, x);
  x += updpp<0x4E, 0xf>(0.f, x);
  x += updpp<0x124, 0xf>(0.f, x);
  x += updpp<0x128, 0xf>(0.f, x);
  x += updpp<0x142, 0xa>(0.f, x);
  x += updpp<0x143, 0xc>(0.f, x);
  return __int_as_float(__builtin_amdgcn_readlane(__float_as_int(x), 63));
}

// ---------------- zero-fill: weights region + Ptg in one launch ----------------
__global__ void k_zero2(float* __restrict__ p1, int n1,
                        float* __restrict__ p2, int n2) {
  int i = blockIdx.x * blockDim.x + threadIdx.x;
  int stride = gridDim.x * blockDim.x;
  float4 z = make_float4(0.f, 0.f, 0.f, 0.f);
  int n14 = n1 >> 2, n24 = n2 >> 2;
  for (int j = i; j < n14; j += stride) ((float4*)p1)[j] = z;
  for (int j = i; j < n24; j += stride) ((float4*)p2)[j] = z;
  int b1 = (n14 << 2) + i; if (b1 < n1) p1[b1] = 0.f;
  int b2 = (n24 << 2) + i; if (b2 < n2) p2[b2] = 0.f;
}

// ---------------- fold weights: Wt[2049][64] ----------------
// cols 0..28: scale*W_in@W_q^T (G); col 29: scale*W_in@b_q (C);
// cols 32..60: W_in@W_out (P); row 2048 = bias row (b_in version).
__global__ __launch_bounds__(64) void k_transform(
    const float* __restrict__ W_in, const float* __restrict__ b_in,
    const float* __restrict__ W_q,  const float* __restrict__ b_q,
    const float* __restrict__ W_out, float* __restrict__ Wt) {
  int i = blockIdx.x;          // 0..2048
  int c = threadIdx.x;         // 0..63
  const float* row = (i < IND) ? (W_in + (size_t)i * DD) : b_in;
  const float* m;
  int strd;
  bool valid = true, dscale = false;
  if (c < OD)                { m = W_q + (size_t)c * DD; strd = 1; dscale = true; }
  else if (c == OD)          { m = b_q;                  strd = 1; dscale = true; }
  else if (c >= 32 && c < 32 + OD) { m = W_out + (c - 32); strd = OD; }
  else                       { m = b_q; strd = 0; valid = false; }
  float a0 = 0.f, a1 = 0.f, a2 = 0.f, a3 = 0.f;
  for (int d = 0; d < DD; d += 4) {
    a0 += row[d + 0] * m[(size_t)(d + 0) * strd];
    a1 += row[d + 1] * m[(size_t)(d + 1) * strd];
    a2 += row[d + 2] * m[(size_t)(d + 2) * strd];
    a3 += row[d + 3] * m[(size_t)(d + 3) * strd];
  }
  float acc = (a0 + a1) + (a2 + a3);
  if (dscale) acc *= (1.0f / sqrtf((float)DD));
  if (!valid) acc = 0.f;
  Wt[(size_t)i * WCOLS + c] = acc;
}

// -- GEMM: double-buffered staging + packed FMA; outputs GPC + chunked Ptg --
__global__ __launch_bounds__(256) void k_gemm(
    const float* __restrict__ x, const float* __restrict__ Wt,
    float* __restrict__ GPC, float* __restrict__ Ptg) {
  __shared__ float xt[2][128][65];
  int tid = threadIdx.x;
  int r = tid & 63;
  int cg16 = __builtin_amdgcn_readfirstlane((tid >> 6) << 4);
  int m0 = blockIdx.x << 6;
  int lr = tid >> 2, lc = tid & 3;
  const float* xl = x + (size_t)(m0 + lr) * IND;
  v2f acc[8];
  #pragma unroll
  for (int i = 0; i < 8; ++i) acc[i] = (v2f){0.f, 0.f};
  // prologue: stage buf 0 (kk = 0)
  #pragma unroll
  for (int j = 0; j < 8; ++j) {
    int k = (lc + 4 * j) << 2;
    float4 v = *(const float4*)(xl + k);
    xt[0][k + 0][lr] = v.x; xt[0][k + 1][lr] = v.y;
    xt[0][k + 2][lr] = v.z; xt[0][k + 3][lr] = v.w;
  }
  __syncthreads();
  for (int kk = 0; kk < IND; kk += 128) {
    int cur = (kk >> 7) & 1;
    if (kk + 128 < IND) {        // stage next tile into the other buffer
      #pragma unroll
      for (int j = 0; j < 8; ++j) {
        int k = (lc + 4 * j) << 2;
        float4 v = *(const float4*)(xl + kk + 128 + k);
        xt[cur ^ 1][k + 0][lr] = v.x; xt[cur ^ 1][k + 1][lr] = v.y;
        xt[cur ^ 1][k + 2][lr] = v.z; xt[cur ^ 1][k + 3][lr] = v.w;
      }
    }
    const float* wb = Wt + (size_t)kk * WCOLS + cg16;
    #pragma unroll 4
    for (int k = 0; k < 128; ++k) {
      float xv = xt[cur][k][r];
      v2f xx = (v2f){xv, xv};
      const float* wk = wb + (size_t)k * WCOLS;
      float4 w0 = *(const float4*)(wk + 0);
      float4 w1 = *(const float4*)(wk + 4);
      float4 w2 = *(const float4*)(wk + 8);
      float4 w3 = *(const float4*)(wk + 12);
      acc[0] = pk_fma(xx, (v2f){w0.x, w0.y}, acc[0]);
      acc[1] = pk_fma(xx, (v2f){w0.z, w0.w}, acc[1]);
      acc[2] = pk_fma(xx, (v2f){w1.x, w1.y}, acc[2]);
      acc[3] = pk_fma(xx, (v2f){w1.z, w1.w}, acc[3]);
      acc[4] = pk_fma(xx, (v2f){w2.x, w2.y}, acc[4]);
      acc[5] = pk_fma(xx, (v2f){w2.z, w2.w}, acc[5]);
      acc[6] = pk_fma(xx, (v2f){w3.x, w3.y}, acc[6]);
      acc[7] = pk_fma(xx, (v2f){w3.z, w3.w}, acc[7]);
    }
    __syncthreads();
  }
  float4 a0 = make_float4(acc[0].x, acc[0].y, acc[1].x, acc[1].y);
  float4 a1 = make_float4(acc[2].x, acc[2].y, acc[3].x, acc[3].y);
  float4 a2 = make_float4(acc[4].x, acc[4].y, acc[5].x, acc[5].y);
  float4 a3 = make_float4(acc[6].x, acc[6].y, acc[7].x, acc[7].y);
  const float* br = Wt + (size_t)IND * WCOLS + cg16;
  float4 b0 = *(const float4*)(br + 0), b1 = *(const float4*)(br + 4);
  float4 b2 = *(const float4*)(br + 8), b3 = *(const float4*)(br + 12);
  a0.x += b0.x; a0.y += b0.y; a0.z += b0.z; a0.w += b0.w;
  a1.x += b1.x; a1.y += b1.y; a1.z += b1.z; a1.w += b1.w;
  a2.x += b2.x; a2.y += b2.y; a2.z += b2.z; a2.w += b2.w;
  a3.x += b3.x; a3.y += b3.y; a3.z += b3.z; a3.w += b3.w;
  if (cg16 < 32) {
    float* o = GPC + (size_t)(m0 + r) * GC + cg16;
    *(float4*)(o + 0) = a0; *(float4*)(o + 4) = a1;
    *(float4*)(o + 8) = a2; *(float4*)(o + 12) = a3;
  } else {
    int bb = m0 >> 9;               // batch
    int jj = (m0 & 511) + r;        // row within batch
    int c0 = cg16 - 32;             // 0 or 16
    float va[16] = {a0.x,a0.y,a0.z,a0.w, a1.x,a1.y,a1.z,a1.w,
                    a2.x,a2.y,a2.z,a2.w, a3.x,a3.y,a3.z,a3.w};
    float* pb = Ptg + (size_t)bb * PTB + (size_t)(jj >> 2) * PTK + (jj & 3);
    #pragma unroll
    for (int cc = 0; cc < 16; ++cc)
      if (c0 + cc < OD) pb[(size_t)(c0 + cc) * 4] = va[cc];
  }
}

// ---------------- scan helpers ----------------
__device__ __forceinline__ void ld_g(v2f* g, const float* gb, int j) {
  const float4* s = (const float4*)(gb + (size_t)j * GC);
  #pragma unroll
  for (int u = 0; u < 8; ++u) {
    float4 v = s[u];
    g[2*u+0] = (v2f){v.x, v.y};
    g[2*u+1] = (v2f){v.z, v.w};
  }
}

// pairs 0..14 cover cols 0..29 (col 29 = C, paired against q-slot 1.0)
__device__ __forceinline__ float score_pk(const v2f* g, const v2f* qp) {
  v2f a0 = pk_fma(qp[0], g[0], (v2f){0.f, 0.f});
  v2f a1 = pk_fma(qp[1], g[1], (v2f){0.f, 0.f});
  v2f a2 = pk_fma(qp[2], g[2], (v2f){0.f, 0.f});
  #pragma unroll
  for (int i = 3; i < 15; i += 3) {
    a0 = pk_fma(qp[i+0], g[i+0], a0);
    a1 = pk_fma(qp[i+1], g[i+1], a1);
    a2 = pk_fma(qp[i+2], g[i+2], a2);
  }
  v2f s = a0 + a1;
  s = s + a2;
  return s.x + s.y;
}

// ---- scan: 1 wave/block, rolling-G regs, VMEM Ptg, tiny LDS (R12, proven) ----
__global__ __launch_bounds__(64, 1) void k_scan(
    const float* __restrict__ GPC, const float* __restrict__ Ptg,
    const int* __restrict__ lens_raw,
    const float* __restrict__ b_out, const int* __restrict__ wsp,
    float* __restrict__ outputs, float* __restrict__ weights) {
  __shared__ __align__(16) float w_lds[640];    // unnormalized e, zero-padded

  int b = blockIdx.x;
  int l = threadIdx.x;
  int len;
  { // int32 / int64 hedge: lens sorted desc, all >0, so word[1]==0 <=> int64
    int probe = lens_raw[1];
    len = (probe == 0) ? lens_raw[2 * b] : lens_raw[b];
  }
  if (len > TT) len = TT;
  if (len < 0) len = 0;
  int ws = wsp[0];

  const float* gb = GPC + (size_t)b * TT * GC;
  for (int j = l; j < 640; j += 64) w_lds[j] = 0.f;
  __syncthreads();

  int k = l & 31, h = l >> 5;
  int kc = (k < OD) ? k : (OD - 1);          // lanes 29..31 mirror row 28
  const float* pvK = Ptg + (size_t)b * PTB + kc * 4;
  float boutk = (k < OD) ? b_out[k] : 0.f;

  float* outb = outputs + (size_t)b * TT * OD;
  float* wb   = weights + (size_t)b * TT * TT;

  // query as packed uniform pairs; init 'fix': ones, last channel = 9
  v2f qp[15];
  #pragma unroll
  for (int i = 0; i < 14; ++i) qp[i] = (v2f){1.f, 1.f};
  qp[14] = (v2f){9.f, 1.f};

  // rolling 192-row G register file: row j -> lane j%64, slot (j>>6)%3
  v2f g0[16], g1[16], g2[16];
  int j0r = l, j1r = 64 + l, j2r = 128 + l;
  ld_g(g0, gb, j0r); ld_g(g1, gb, j1r); ld_g(g2, gb, j2r);

  int jlo = 0;
  int jhi = (ws < len - 1) ? ws : (len - 1);

  float m_run = -3.0e38f;   // deferred running max
  int t = 0;
  for (; t < len; ++t) {
    int qb = jlo >> 2;                       // 4-row chunk index
    // ---- Ptg reads (VMEM pipe; overlap the DS/w-stream below) ----
    float4 rp[17];
    {
      const float* pr = pvK + (size_t)(qb + h) * PTK;
      #pragma unroll
      for (int i = 0; i < 17; ++i) rp[i] = *(const float4*)(pr + (size_t)(2 * i) * PTK);
    }
    __builtin_amdgcn_sched_barrier(0);
    // ---- scores from register slots (packed f32 FMA, q uniform) ----
    float s0 = score_pk(g0, qp);
    float s1 = score_pk(g1, qp);
    float s2 = score_pk(g2, qp);
    bool v0 = (j0r >= jlo) & (j0r <= jhi);
    bool v1 = (j1r >= jlo) & (j1r <= jhi);
    bool v2 = (j2r >= jlo) & (j2r <= jhi);
    const float NEG = -3.0e38f;
    float mx0 = fmaxf(fmaxf(v0 ? s0 : NEG, v1 ? s1 : NEG), v2 ? s2 : NEG);
    // speculative exp with running max; rare fixup when band violated
    float mx = m_run;
    float e0 = v0 ? __expf(s0 - mx) : 0.f;
    float e1 = v1 ? __expf(s1 - mx) : 0.f;
    float e2 = v2 ? __expf(s2 - mx) : 0.f;
    if (!(__all(mx0 <= m_run + 8.0f) && __any(mx0 >= m_run - 20.0f))) {
      mx = red_max64(mx0);
      m_run = mx;
      e0 = v0 ? __expf(s0 - mx) : 0.f;
      e1 = v1 ? __expf(s1 - mx) : 0.f;
      e2 = v2 ? __expf(s2 - mx) : 0.f;
    }
    // unnormalized e scatter into LDS (row j%64 == lane: conflict-free)
    if (l == 0 && jlo > 0) w_lds[jlo - 1] = 0.f;  // evict stale window entry
    if (v0) w_lds[j0r] = e0;
    if (v1) w_lds[j1r] = e1;
    if (v2) w_lds[j2r] = e2;
    // sum reduce + rcp + weight stores: cover for the w-read drain below
    float sm = red_sum64(e0 + e1 + e2);
    float invS = __builtin_amdgcn_rcpf(sm);
    float* wrow = wb + (size_t)t * TT;
    if (v0) wrow[j0r] = e0 * invS;
    if (v1) wrow[j1r] = e1 * invS;
    if (v2) wrow[j2r] = e2 * invS;
    // ---- PV: w from LDS (in-order after e-writes), P from rp registers ----
    v2f pA = (v2f){0.f, 0.f}, pB = (v2f){0.f, 0.f};
    v2f pC = (v2f){0.f, 0.f}, pD = (v2f){0.f, 0.f};
    {
      const float* wr = w_lds + ((qb + h) << 2);
      #pragma unroll
      for (int i = 0; i < 17; i += 2) {
        float4 wv = *(const float4*)(wr + (i << 3));
        pA = pk_fma((v2f){wv.x, wv.y}, (v2f){rp[i].x, rp[i].y}, pA);
        pB = pk_fma((v2f){wv.z, wv.w}, (v2f){rp[i].z, rp[i].w}, pB);
      }
      #pragma unroll
      for (int i = 1; i < 17; i += 2) {
        float4 wv = *(const float4*)(wr + (i << 3));
        pC = pk_fma((v2f){wv.x, wv.y}, (v2f){rp[i].x, rp[i].y}, pC);
        pD = pk_fma((v2f){wv.z, wv.w}, (v2f){rp[i].z, rp[i].w}, pD);
      }
    }
    v2f ps = (pA + pC) + (pB + pD);
    float tot = ps.x + ps.y;
    // cross-half combine: pure-VALU permlane32_swap (proven R8/R10/R12)
    float tc = tot;
    asm("v_permlane32_swap_b32 %0, %1" : "+v"(tot), "+v"(tc));
    float comb = tot + tc;
    float nq = comb * invS + boutk;
    if (h == 0 && k < OD) outb[(size_t)t * OD + k] = nq;
    // broadcast new query into packed uniform pairs (on-chain)
    #pragma unroll
    for (int kk = 0; kk < 14; ++kk) {
      float lo = __int_as_float(__builtin_amdgcn_readlane(__float_as_int(nq), 2*kk));
      float hi = __int_as_float(__builtin_amdgcn_readlane(__float_as_int(nq), 2*kk+1));
      qp[kk] = (v2f){lo, hi};
    }
    qp[14] = (v2f){__int_as_float(__builtin_amdgcn_readlane(__float_as_int(nq), 28)), 1.0f};
    // rolling refill, prefetch distance 2 (fully off-chain)
    int jnew = t + 2 + ws;
    if (jnew >= 192 && jnew < TT) {
      int sl = (jnew >> 6) % 3;
      int ln = jnew & 63;
      if (sl == 0)      { if (l == ln) { ld_g(g0, gb, jnew); j0r = jnew; } }
      else if (sl == 1) { if (l == ln) { ld_g(g1, gb, jnew); j1r = jnew; } }
      else              { if (l == ln) { ld_g(g2, gb, jnew); j2r = jnew; } }
    }
    // advance window
    jlo = (t + 1) - ws; if (jlo < 0) jlo = 0;
    jhi = (t + 1) + ws; if (jhi > len - 1) jhi = len - 1;
  }
  // dead tail: outputs = b_out, weights stay zero
  for (; t < TT; ++t)
    if (l < OD) outb[(size_t)t * OD + l] = boutk;
}

extern "C" void kernel_launch(void* const* d_in, const int* in_sizes, int n_in,
                              void* d_out, int out_size, void* d_ws, size_t ws_size,
                              hipStream_t stream) {
  const float* x     = (const float*)d_in[0];
  const int*   lens  = (const int*)d_in[1];
  const float* W_in  = (const float*)d_in[2];
  const float* b_in  = (const float*)d_in[3];
  const float* W_q   = (const float*)d_in[4];
  const float* b_q   = (const float*)d_in[5];
  const float* W_out = (const float*)d_in[6];
  const float* b_out = (const float*)d_in[7];
  const int*   wsp   = (const int*)d_in[8];
  float* out = (float*)d_out;

  float* Wt  = (float*)d_ws;                      // [2049][64]
  float* GPC = Wt + (size_t)(IND + 1) * WCOLS;    // [B*T][32]
  float* Ptg = GPC + (size_t)BB * TT * GC;        // [B][160][29][4]

  float* outputs = out;
  float* weights = out + (size_t)BB * TT * OD;

  // outputs region is fully rewritten by k_scan; zero only weights + Ptg
  k_zero2<<<1024, 256, 0, stream>>>(weights, BB * TT * TT, Ptg, BB * PTB);
  k_transform<<<IND + 1, 64, 0, stream>>>(W_in, b_in, W_q, b_q, W_out, Wt);
  k_gemm<<<(BB * TT) / 64, 256, 0, stream>>>(x, Wt, GPC, Ptg);
  k_scan<<<BB, 64, 0, stream>>>(GPC, Ptg, lens, b_out, wsp, outputs, weights);
}

// Round 17
// 807.539 us; speedup vs baseline: 1.2560x; 1.0717x over previous
//
#include <hip/hip_runtime.h>
#include <math.h>

#define BB 32
#define TT 512
#define IND 2048
#define DD 512
#define OD 29
#define WCOLS 64   // Wt cols
#define GC 32      // GPC cols (G + C)
#define PTK 116    // Ptg chunk stride: 29 k's * 4 floats
#define PTB 18560  // Ptg per-batch floats: 160 chunks * 116

typedef float v2f __attribute__((ext_vector_type(2)));

__device__ __forceinline__ v2f pk_fma(v2f a, v2f b, v2f c) {
  v2f d;
  asm("v_pk_fma_f32 %0, %1, %2, %3" : "=v"(d) : "v"(a), "v"(b), "v"(c));
  return d;
}

template<int CTRL, int RM>
__device__ __forceinline__ float updpp(float idv, float x) {
  return __int_as_float(__builtin_amdgcn_update_dpp(
      __float_as_int(idv), __float_as_int(x), CTRL, RM, 0xf, false));
}

// All-VALU wave64 reductions (DPP ladder), broadcast via readlane 63.
__device__ __forceinline__ float red_max64(float x) {
  const float ID = -3.0e38f;
  x = fmaxf(x, updpp<0xB1, 0xf>(ID, x));
  x = fmaxf(x, updpp<0x4E, 0xf>(ID, x));
  x = fmaxf(x, updpp<0x124, 0xf>(ID, x));
  x = fmaxf(x, updpp<0x128, 0xf>(ID, x));
  x = fmaxf(x, updpp<0x142, 0xa>(ID, x));
  x = fmaxf(x, updpp<0x143, 0xc>(ID, x));
  return __int_as_float(__builtin_amdgcn_readlane(__float_as_int(x), 63));
}

__device__ __forceinline__ float red_sum64(float x) {
  x += updpp<0xB1, 0xf>(0.f, x);
  x += updpp<0x4E, 0xf>(0.f, x);
  x += updpp<0x124, 0xf>(0.f, x);
  x += updpp<0x128, 0xf>(0.f, x);
  x += updpp<0x142, 0xa>(0.f, x);
  x += updpp<0x143, 0xc>(0.f, x);
  return __int_as_float(__builtin_amdgcn_readlane(__float_as_int(x), 63));
}

// ---- fold weights: Wt[2049][64]; also zero weights-out + Ptg (overlapped) ----
// cols 0..28: scale*W_in@W_q^T (G); col 29: scale*W_in@b_q (C);
// cols 32..60: W_in@W_out (P); row 2048 = bias row (b_in version).
__global__ __launch_bounds__(64) void k_transform(
    const float* __restrict__ W_in, const float* __restrict__ b_in,
    const float* __restrict__ W_q,  const float* __restrict__ b_q,
    const float* __restrict__ W_out, float* __restrict__ Wt,
    float* __restrict__ zero1, int n1,      // weights region (multiple of 4)
    float* __restrict__ zero2, int n2) {    // Ptg region (multiple of 4)
  int i = blockIdx.x;          // 0..2048
  int c = threadIdx.x;         // 0..63
  // grid-stride zeroing; stores overlap the dot-product compute below
  {
    int gid = blockIdx.x * 64 + c;
    int gstride = gridDim.x * 64;
    float4 z = make_float4(0.f, 0.f, 0.f, 0.f);
    for (int j = gid; j < (n1 >> 2); j += gstride) ((float4*)zero1)[j] = z;
    for (int j = gid; j < (n2 >> 2); j += gstride) ((float4*)zero2)[j] = z;
  }
  const float* row = (i < IND) ? (W_in + (size_t)i * DD) : b_in;
  const float* m;
  int strd;
  bool valid = true, dscale = false;
  if (c < OD)                { m = W_q + (size_t)c * DD; strd = 1; dscale = true; }
  else if (c == OD)          { m = b_q;                  strd = 1; dscale = true; }
  else if (c >= 32 && c < 32 + OD) { m = W_out + (c - 32); strd = OD; }
  else                       { m = b_q; strd = 0; valid = false; }
  float a0 = 0.f, a1 = 0.f, a2 = 0.f, a3 = 0.f;
  for (int d = 0; d < DD; d += 4) {
    a0 += row[d + 0] * m[(size_t)(d + 0) * strd];
    a1 += row[d + 1] * m[(size_t)(d + 1) * strd];
    a2 += row[d + 2] * m[(size_t)(d + 2) * strd];
    a3 += row[d + 3] * m[(size_t)(d + 3) * strd];
  }
  float acc = (a0 + a1) + (a2 + a3);
  if (dscale) acc *= (1.0f / sqrtf((float)DD));
  if (!valid) acc = 0.f;
  Wt[(size_t)i * WCOLS + c] = acc;
}

// -- GEMM (R12-proven form): GPC (G+C, 32 cols) + Ptg (chunked [j/4][k][j%4]) --
__global__ __launch_bounds__(256) void k_gemm(
    const float* __restrict__ x, const float* __restrict__ Wt,
    float* __restrict__ GPC, float* __restrict__ Ptg) {
  __shared__ float xt[128][65];
  int tid = threadIdx.x;
  int r = tid & 63;
  int cg16 = __builtin_amdgcn_readfirstlane((tid >> 6) << 4);
  int m0 = blockIdx.x << 6;
  int lr = tid >> 2, lc = tid & 3;
  const float* xl = x + (size_t)(m0 + lr) * IND;
  float4 a0 = make_float4(0,0,0,0), a1 = a0, a2 = a0, a3 = a0;
  for (int kk = 0; kk < IND; kk += 128) {
    __syncthreads();
    #pragma unroll
    for (int j = 0; j < 8; ++j) {
      int k = (lc + 4 * j) << 2;
      float4 v = *(const float4*)(xl + kk + k);
      xt[k + 0][lr] = v.x; xt[k + 1][lr] = v.y;
      xt[k + 2][lr] = v.z; xt[k + 3][lr] = v.w;
    }
    __syncthreads();
    const float* wb = Wt + (size_t)kk * WCOLS + cg16;
    #pragma unroll 4
    for (int k = 0; k < 128; ++k) {
      float xv = xt[k][r];
      const float* wk = wb + (size_t)k * WCOLS;
      float4 w0 = *(const float4*)(wk + 0);
      float4 w1 = *(const float4*)(wk + 4);
      float4 w2 = *(const float4*)(wk + 8);
      float4 w3 = *(const float4*)(wk + 12);
      a0.x += xv * w0.x; a0.y += xv * w0.y; a0.z += xv * w0.z; a0.w += xv * w0.w;
      a1.x += xv * w1.x; a1.y += xv * w1.y; a1.z += xv * w1.z; a1.w += xv * w1.w;
      a2.x += xv * w2.x; a2.y += xv * w2.y; a2.z += xv * w2.z; a2.w += xv * w2.w;
      a3.x += xv * w3.x; a3.y += xv * w3.y; a3.z += xv * w3.z; a3.w += xv * w3.w;
    }
  }
  const float* br = Wt + (size_t)IND * WCOLS + cg16;
  float4 b0 = *(const float4*)(br + 0), b1 = *(const float4*)(br + 4);
  float4 b2 = *(const float4*)(br + 8), b3 = *(const float4*)(br + 12);
  a0.x += b0.x; a0.y += b0.y; a0.z += b0.z; a0.w += b0.w;
  a1.x += b1.x; a1.y += b1.y; a1.z += b1.z; a1.w += b1.w;
  a2.x += b2.x; a2.y += b2.y; a2.z += b2.z; a2.w += b2.w;
  a3.x += b3.x; a3.y += b3.y; a3.z += b3.z; a3.w += b3.w;
  if (cg16 < 32) {
    float* o = GPC + (size_t)(m0 + r) * GC + cg16;
    *(float4*)(o + 0) = a0; *(float4*)(o + 4) = a1;
    *(float4*)(o + 8) = a2; *(float4*)(o + 12) = a3;
  } else {
    int bb = m0 >> 9;               // batch
    int jj = (m0 & 511) + r;        // row within batch
    int c0 = cg16 - 32;             // 0 or 16
    float va[16] = {a0.x,a0.y,a0.z,a0.w, a1.x,a1.y,a1.z,a1.w,
                    a2.x,a2.y,a2.z,a2.w, a3.x,a3.y,a3.z,a3.w};
    float* pb = Ptg + (size_t)bb * PTB + (size_t)(jj >> 2) * PTK + (jj & 3);
    #pragma unroll
    for (int cc = 0; cc < 16; ++cc)
      if (c0 + cc < OD) pb[(size_t)(c0 + cc) * 4] = va[cc];
  }
}

// ---------------- scan helpers ----------------
__device__ __forceinline__ void ld_g(v2f* g, const float* gb, int j) {
  const float4* s = (const float4*)(gb + (size_t)j * GC);
  #pragma unroll
  for (int u = 0; u < 8; ++u) {
    float4 v = s[u];
    g[2*u+0] = (v2f){v.x, v.y};
    g[2*u+1] = (v2f){v.z, v.w};
  }
}

// pairs 0..14 cover cols 0..29 (col 29 = C, paired against q-slot 1.0)
__device__ __forceinline__ float score_pk(const v2f* g, const v2f* qp) {
  v2f a0 = pk_fma(qp[0], g[0], (v2f){0.f, 0.f});
  v2f a1 = pk_fma(qp[1], g[1], (v2f){0.f, 0.f});
  v2f a2 = pk_fma(qp[2], g[2], (v2f){0.f, 0.f});
  #pragma unroll
  for (int i = 3; i < 15; i += 3) {
    a0 = pk_fma(qp[i+0], g[i+0], a0);
    a1 = pk_fma(qp[i+1], g[i+1], a1);
    a2 = pk_fma(qp[i+2], g[i+2], a2);
  }
  v2f s = a0 + a1;
  s = s + a2;
  return s.x + s.y;
}

// ---- scan: 1 wave/block, rolling-G regs, VMEM Ptg, tiny LDS (R12, proven) ----
__global__ __launch_bounds__(64, 1) void k_scan(
    const float* __restrict__ GPC, const float* __restrict__ Ptg,
    const int* __restrict__ lens_raw,
    const float* __restrict__ b_out, const int* __restrict__ wsp,
    float* __restrict__ outputs, float* __restrict__ weights) {
  __shared__ __align__(16) float w_lds[640];    // unnormalized e, zero-padded

  int b = blockIdx.x;
  int l = threadIdx.x;
  int len;
  { // int32 / int64 hedge: lens sorted desc, all >0, so word[1]==0 <=> int64
    int probe = lens_raw[1];
    len = (probe == 0) ? lens_raw[2 * b] : lens_raw[b];
  }
  if (len > TT) len = TT;
  if (len < 0) len = 0;
  int ws = wsp[0];

  const float* gb = GPC + (size_t)b * TT * GC;
  for (int j = l; j < 640; j += 64) w_lds[j] = 0.f;
  __syncthreads();

  int k = l & 31, h = l >> 5;
  int kc = (k < OD) ? k : (OD - 1);          // lanes 29..31 mirror row 28
  const float* pvK = Ptg + (size_t)b * PTB + kc * 4;
  float boutk = (k < OD) ? b_out[k] : 0.f;

  float* outb = outputs + (size_t)b * TT * OD;
  float* wb   = weights + (size_t)b * TT * TT;

  // query as packed uniform pairs; init 'fix': ones, last channel = 9
  v2f qp[15];
  #pragma unroll
  for (int i = 0; i < 14; ++i) qp[i] = (v2f){1.f, 1.f};
  qp[14] = (v2f){9.f, 1.f};

  // rolling 192-row G register file: row j -> lane j%64, slot (j>>6)%3
  v2f g0[16], g1[16], g2[16];
  int j0r = l, j1r = 64 + l, j2r = 128 + l;
  ld_g(g0, gb, j0r); ld_g(g1, gb, j1r); ld_g(g2, gb, j2r);

  int jlo = 0;
  int jhi = (ws < len - 1) ? ws : (len - 1);

  float m_run = -3.0e38f;   // deferred running max
  int t = 0;
  for (; t < len; ++t) {
    int qb = jlo >> 2;                       // 4-row chunk index
    // ---- Ptg reads (VMEM pipe; overlap the DS/w-stream below) ----
    float4 rp[17];
    {
      const float* pr = pvK + (size_t)(qb + h) * PTK;
      #pragma unroll
      for (int i = 0; i < 17; ++i) rp[i] = *(const float4*)(pr + (size_t)(2 * i) * PTK);
    }
    __builtin_amdgcn_sched_barrier(0);
    // ---- scores from register slots (packed f32 FMA, q uniform) ----
    float s0 = score_pk(g0, qp);
    float s1 = score_pk(g1, qp);
    float s2 = score_pk(g2, qp);
    bool v0 = (j0r >= jlo) & (j0r <= jhi);
    bool v1 = (j1r >= jlo) & (j1r <= jhi);
    bool v2 = (j2r >= jlo) & (j2r <= jhi);
    const float NEG = -3.0e38f;
    float mx0 = fmaxf(fmaxf(v0 ? s0 : NEG, v1 ? s1 : NEG), v2 ? s2 : NEG);
    // speculative exp with running max; rare fixup when band violated
    float mx = m_run;
    float e0 = v0 ? __expf(s0 - mx) : 0.f;
    float e1 = v1 ? __expf(s1 - mx) : 0.f;
    float e2 = v2 ? __expf(s2 - mx) : 0.f;
    if (!(__all(mx0 <= m_run + 8.0f) && __any(mx0 >= m_run - 20.0f))) {
      mx = red_max64(mx0);
      m_run = mx;
      e0 = v0 ? __expf(s0 - mx) : 0.f;
      e1 = v1 ? __expf(s1 - mx) : 0.f;
      e2 = v2 ? __expf(s2 - mx) : 0.f;
    }
    // unnormalized e scatter into LDS (row j%64 == lane: conflict-free)
    if (l == 0 && jlo > 0) w_lds[jlo - 1] = 0.f;  // evict stale window entry
    if (v0) w_lds[j0r] = e0;
    if (v1) w_lds[j1r] = e1;
    if (v2) w_lds[j2r] = e2;
    // sum reduce + rcp + weight stores: cover for the w-read drain below
    float sm = red_sum64(e0 + e1 + e2);
    float invS = __builtin_amdgcn_rcpf(sm);
    float* wrow = wb + (size_t)t * TT;
    if (v0) wrow[j0r] = e0 * invS;
    if (v1) wrow[j1r] = e1 * invS;
    if (v2) wrow[j2r] = e2 * invS;
    // ---- PV: w from LDS (in-order after e-writes), P from rp registers ----
    v2f pA = (v2f){0.f, 0.f}, pB = (v2f){0.f, 0.f};
    v2f pC = (v2f){0.f, 0.f}, pD = (v2f){0.f, 0.f};
    {
      const float* wr = w_lds + ((qb + h) << 2);
      #pragma unroll
      for (int i = 0; i < 17; i += 2) {
        float4 wv = *(const float4*)(wr + (i << 3));
        pA = pk_fma((v2f){wv.x, wv.y}, (v2f){rp[i].x, rp[i].y}, pA);
        pB = pk_fma((v2f){wv.z, wv.w}, (v2f){rp[i].z, rp[i].w}, pB);
      }
      #pragma unroll
      for (int i = 1; i < 17; i += 2) {
        float4 wv = *(const float4*)(wr + (i << 3));
        pC = pk_fma((v2f){wv.x, wv.y}, (v2f){rp[i].x, rp[i].y}, pC);
        pD = pk_fma((v2f){wv.z, wv.w}, (v2f){rp[i].z, rp[i].w}, pD);
      }
    }
    v2f ps = (pA + pC) + (pB + pD);
    float tot = ps.x + ps.y;
    // cross-half combine: pure-VALU permlane32_swap (proven R8/R10/R12)
    float tc = tot;
    asm("v_permlane32_swap_b32 %0, %1" : "+v"(tot), "+v"(tc));
    float comb = tot + tc;
    float nq = comb * invS + boutk;
    if (h == 0 && k < OD) outb[(size_t)t * OD + k] = nq;
    // broadcast new query into packed uniform pairs (on-chain)
    #pragma unroll
    for (int kk = 0; kk < 14; ++kk) {
      float lo = __int_as_float(__builtin_amdgcn_readlane(__float_as_int(nq), 2*kk));
      float hi = __int_as_float(__builtin_amdgcn_readlane(__float_as_int(nq), 2*kk+1));
      qp[kk] = (v2f){lo, hi};
    }
    qp[14] = (v2f){__int_as_float(__builtin_amdgcn_readlane(__float_as_int(nq), 28)), 1.0f};
    // rolling refill, prefetch distance 2 (fully off-chain)
    int jnew = t + 2 + ws;
    if (jnew >= 192 && jnew < TT) {
      int sl = (jnew >> 6) % 3;
      int ln = jnew & 63;
      if (sl == 0)      { if (l == ln) { ld_g(g0, gb, jnew); j0r = jnew; } }
      else if (sl == 1) { if (l == ln) { ld_g(g1, gb, jnew); j1r = jnew; } }
      else              { if (l == ln) { ld_g(g2, gb, jnew); j2r = jnew; } }
    }
    // advance window
    jlo = (t + 1) - ws; if (jlo < 0) jlo = 0;
    jhi = (t + 1) + ws; if (jhi > len - 1) jhi = len - 1;
  }
  // dead tail: outputs = b_out, weights stay zero
  for (; t < TT; ++t)
    if (l < OD) outb[(size_t)t * OD + l] = boutk;
}

extern "C" void kernel_launch(void* const* d_in, const int* in_sizes, int n_in,
                              void* d_out, int out_size, void* d_ws, size_t ws_size,
                              hipStream_t stream) {
  const float* x     = (const float*)d_in[0];
  const int*   lens  = (const int*)d_in[1];
  const float* W_in  = (const float*)d_in[2];
  const float* b_in  = (const float*)d_in[3];
  const float* W_q   = (const float*)d_in[4];
  const float* b_q   = (const float*)d_in[5];
  const float* W_out = (const float*)d_in[6];
  const float* b_out = (const float*)d_in[7];
  const int*   wsp   = (const int*)d_in[8];
  float* out = (float*)d_out;

  float* Wt  = (float*)d_ws;                      // [2049][64]
  float* GPC = Wt + (size_t)(IND + 1) * WCOLS;    // [B*T][32]
  float* Ptg = GPC + (size_t)BB * TT * GC;        // [B][160][29][4]

  float* outputs = out;
  float* weights = out + (size_t)BB * TT * OD;

  // transform folds weights AND zeroes weights-out + Ptg (overlapped stores);
  // outputs region is fully rewritten by k_scan each call.
  k_transform<<<IND + 1, 64, 0, stream>>>(W_in, b_in, W_q, b_q, W_out, Wt,
                                          weights, BB * TT * TT, Ptg, BB * PTB);
  k_gemm<<<(BB * TT) / 64, 256, 0, stream>>>(x, Wt, GPC, Ptg);
  k_scan<<<BB, 64, 0, stream>>>(GPC, Ptg, lens, b_out, wsp, outputs, weights);
}

// Round 19
// 806.372 us; speedup vs baseline: 1.2578x; 1.0014x over previous
//
#include <hip/hip_runtime.h>
#include <math.h>

#define BB 32
#define TT 512
#define IND 2048
#define DD 512
#define OD 29
#define WCOLS 64   // Wt cols
#define GC 32      // GPC cols (G + C)
#define PTK 116    // Ptg chunk stride: 29 k's * 4 floats
#define PTB 18560  // Ptg per-batch floats: 160 chunks * 116

typedef float v2f __attribute__((ext_vector_type(2)));

__device__ __forceinline__ v2f pk_fma(v2f a, v2f b, v2f c) {
  v2f d;
  asm("v_pk_fma_f32 %0, %1, %2, %3" : "=v"(d) : "v"(a), "v"(b), "v"(c));
  return d;
}

template<int CTRL, int RM>
__device__ __forceinline__ float updpp(float idv, float x) {
  return __int_as_float(__builtin_amdgcn_update_dpp(
      __float_as_int(idv), __float_as_int(x), CTRL, RM, 0xf, false));
}

// All-VALU wave64 reductions (DPP ladder), broadcast via readlane 63.
__device__ __forceinline__ float red_max64(float x) {
  const float ID = -3.0e38f;
  x = fmaxf(x, updpp<0xB1, 0xf>(ID, x));
  x = fmaxf(x, updpp<0x4E, 0xf>(ID, x));
  x = fmaxf(x, updpp<0x124, 0xf>(ID, x));
  x = fmaxf(x, updpp<0x128, 0xf>(ID, x));
  x = fmaxf(x, updpp<0x142, 0xa>(ID, x));
  x = fmaxf(x, updpp<0x143, 0xc>(ID, x));
  return __int_as_float(__builtin_amdgcn_readlane(__float_as_int(x), 63));
}

__device__ __forceinline__ float red_sum64(float x) {
  x += updpp<0xB1, 0xf>(0.f, x);
  x += updpp<0x4E, 0xf>(0.f, x);
  x += updpp<0x124, 0xf>(0.f, x);
  x += updpp<0x128, 0xf>(0.f, x);
  x += updpp<0x142, 0xa>(0.f, x);
  x += updpp<0x143, 0xc>(0.f, x);
  return __int_as_float(__builtin_amdgcn_readlane(__float_as_int(x), 63));
}

// ---- fold weights: Wt[2049][64]; also zero weights-out + Ptg (overlapped) ----
// cols 0..28: scale*W_in@W_q^T (G); col 29: scale*W_in@b_q (C);
// cols 32..60: W_in@W_out (P); row 2048 = bias row (b_in version).
__global__ __launch_bounds__(64) void k_transform(
    const float* __restrict__ W_in, const float* __restrict__ b_in,
    const float* __restrict__ W_q,  const float* __restrict__ b_q,
    const float* __restrict__ W_out, float* __restrict__ Wt,
    float* __restrict__ zero1, int n1,      // weights region (multiple of 4)
    float* __restrict__ zero2, int n2) {    // Ptg region (multiple of 4)
  int i = blockIdx.x;          // 0..2048
  int c = threadIdx.x;         // 0..63
  // grid-stride zeroing; stores overlap the dot-product compute below
  {
    int gid = blockIdx.x * 64 + c;
    int gstride = gridDim.x * 64;
    float4 z = make_float4(0.f, 0.f, 0.f, 0.f);
    for (int j = gid; j < (n1 >> 2); j += gstride) ((float4*)zero1)[j] = z;
    for (int j = gid; j < (n2 >> 2); j += gstride) ((float4*)zero2)[j] = z;
  }
  const float* row = (i < IND) ? (W_in + (size_t)i * DD) : b_in;
  const float* m;
  int strd;
  bool valid = true, dscale = false;
  if (c < OD)                { m = W_q + (size_t)c * DD; strd = 1; dscale = true; }
  else if (c == OD)          { m = b_q;                  strd = 1; dscale = true; }
  else if (c >= 32 && c < 32 + OD) { m = W_out + (c - 32); strd = OD; }
  else                       { m = b_q; strd = 0; valid = false; }
  float a0 = 0.f, a1 = 0.f, a2 = 0.f, a3 = 0.f;
  for (int d = 0; d < DD; d += 4) {
    a0 += row[d + 0] * m[(size_t)(d + 0) * strd];
    a1 += row[d + 1] * m[(size_t)(d + 1) * strd];
    a2 += row[d + 2] * m[(size_t)(d + 2) * strd];
    a3 += row[d + 3] * m[(size_t)(d + 3) * strd];
  }
  float acc = (a0 + a1) + (a2 + a3);
  if (dscale) acc *= (1.0f / sqrtf((float)DD));
  if (!valid) acc = 0.f;
  Wt[(size_t)i * WCOLS + c] = acc;
}

// -- GEMM (R12-proven form): GPC (G+C, 32 cols) + Ptg (chunked [j/4][k][j%4]) --
__global__ __launch_bounds__(256) void k_gemm(
    const float* __restrict__ x, const float* __restrict__ Wt,
    float* __restrict__ GPC, float* __restrict__ Ptg) {
  __shared__ float xt[128][65];
  int tid = threadIdx.x;
  int r = tid & 63;
  int cg16 = __builtin_amdgcn_readfirstlane((tid >> 6) << 4);
  int m0 = blockIdx.x << 6;
  int lr = tid >> 2, lc = tid & 3;
  const float* xl = x + (size_t)(m0 + lr) * IND;
  float4 a0 = make_float4(0,0,0,0), a1 = a0, a2 = a0, a3 = a0;
  for (int kk = 0; kk < IND; kk += 128) {
    __syncthreads();
    #pragma unroll
    for (int j = 0; j < 8; ++j) {
      int k = (lc + 4 * j) << 2;
      float4 v = *(const float4*)(xl + kk + k);
      xt[k + 0][lr] = v.x; xt[k + 1][lr] = v.y;
      xt[k + 2][lr] = v.z; xt[k + 3][lr] = v.w;
    }
    __syncthreads();
    const float* wb = Wt + (size_t)kk * WCOLS + cg16;
    #pragma unroll 4
    for (int k = 0; k < 128; ++k) {
      float xv = xt[k][r];
      const float* wk = wb + (size_t)k * WCOLS;
      float4 w0 = *(const float4*)(wk + 0);
      float4 w1 = *(const float4*)(wk + 4);
      float4 w2 = *(const float4*)(wk + 8);
      float4 w3 = *(const float4*)(wk + 12);
      a0.x += xv * w0.x; a0.y += xv * w0.y; a0.z += xv * w0.z; a0.w += xv * w0.w;
      a1.x += xv * w1.x; a1.y += xv * w1.y; a1.z += xv * w1.z; a1.w += xv * w1.w;
      a2.x += xv * w2.x; a2.y += xv * w2.y; a2.z += xv * w2.z; a2.w += xv * w2.w;
      a3.x += xv * w3.x; a3.y += xv * w3.y; a3.z += xv * w3.z; a3.w += xv * w3.w;
    }
  }
  const float* br = Wt + (size_t)IND * WCOLS + cg16;
  float4 b0 = *(const float4*)(br + 0), b1 = *(const float4*)(br + 4);
  float4 b2 = *(const float4*)(br + 8), b3 = *(const float4*)(br + 12);
  a0.x += b0.x; a0.y += b0.y; a0.z += b0.z; a0.w += b0.w;
  a1.x += b1.x; a1.y += b1.y; a1.z += b1.z; a1.w += b1.w;
  a2.x += b2.x; a2.y += b2.y; a2.z += b2.z; a2.w += b2.w;
  a3.x += b3.x; a3.y += b3.y; a3.z += b3.z; a3.w += b3.w;
  if (cg16 < 32) {
    float* o = GPC + (size_t)(m0 + r) * GC + cg16;
    *(float4*)(o + 0) = a0; *(float4*)(o + 4) = a1;
    *(float4*)(o + 8) = a2; *(float4*)(o + 12) = a3;
  } else {
    int bb = m0 >> 9;               // batch
    int jj = (m0 & 511) + r;        // row within batch
    int c0 = cg16 - 32;             // 0 or 16
    float va[16] = {a0.x,a0.y,a0.z,a0.w, a1.x,a1.y,a1.z,a1.w,
                    a2.x,a2.y,a2.z,a2.w, a3.x,a3.y,a3.z,a3.w};
    float* pb = Ptg + (size_t)bb * PTB + (size_t)(jj >> 2) * PTK + (jj & 3);
    #pragma unroll
    for (int cc = 0; cc < 16; ++cc)
      if (c0 + cc < OD) pb[(size_t)(c0 + cc) * 4] = va[cc];
  }
}

// ---------------- scan helpers ----------------
__device__ __forceinline__ void ld_g(v2f* g, const float* gb, int j) {
  const float4* s = (const float4*)(gb + (size_t)j * GC);
  #pragma unroll
  for (int u = 0; u < 8; ++u) {
    float4 v = s[u];
    g[2*u+0] = (v2f){v.x, v.y};
    g[2*u+1] = (v2f){v.z, v.w};
  }
}

// pairs 0..14 cover cols 0..29 (col 29 = C, paired against q-slot 1.0)
__device__ __forceinline__ float score_pk(const v2f* g, const v2f* qp) {
  v2f a0 = pk_fma(qp[0], g[0], (v2f){0.f, 0.f});
  v2f a1 = pk_fma(qp[1], g[1], (v2f){0.f, 0.f});
  v2f a2 = pk_fma(qp[2], g[2], (v2f){0.f, 0.f});
  #pragma unroll
  for (int i = 3; i < 15; i += 3) {
    a0 = pk_fma(qp[i+0], g[i+0], a0);
    a1 = pk_fma(qp[i+1], g[i+1], a1);
    a2 = pk_fma(qp[i+2], g[i+2], a2);
  }
  v2f s = a0 + a1;
  s = s + a2;
  return s.x + s.y;
}

// ---- scan: 1 wave/block, rolling-G regs, VMEM Ptg, tiny LDS (R17, proven) ----
__global__ __launch_bounds__(64, 1) void k_scan(
    const float* __restrict__ GPC, const float* __restrict__ Ptg,
    const int* __restrict__ lens_raw,
    const float* __restrict__ b_out, const int* __restrict__ wsp,
    float* __restrict__ outputs, float* __restrict__ weights) {
  __shared__ __align__(16) float w_lds[640];    // unnormalized e, zero-padded

  int b = blockIdx.x;
  int l = threadIdx.x;
  int len;
  { // int32 / int64 hedge: lens sorted desc, all >0, so word[1]==0 <=> int64
    int probe = lens_raw[1];
    len = (probe == 0) ? lens_raw[2 * b] : lens_raw[b];
  }
  if (len > TT) len = TT;
  if (len < 0) len = 0;
  int ws = wsp[0];

  const float* gb = GPC + (size_t)b * TT * GC;
  for (int j = l; j < 640; j += 64) w_lds[j] = 0.f;
  __syncthreads();

  int k = l & 31, h = l >> 5;
  int kc = (k < OD) ? k : (OD - 1);          // lanes 29..31 mirror row 28
  const float* pvK = Ptg + (size_t)b * PTB + kc * 4;
  float boutk = (k < OD) ? b_out[k] : 0.f;

  float* outb = outputs + (size_t)b * TT * OD;
  float* wb   = weights + (size_t)b * TT * TT;

  // query as packed uniform pairs; init 'fix': ones, last channel = 9
  v2f qp[15];
  #pragma unroll
  for (int i = 0; i < 14; ++i) qp[i] = (v2f){1.f, 1.f};
  qp[14] = (v2f){9.f, 1.f};

  // rolling 192-row G register file: row j -> lane j%64, slot (j>>6)%3
  v2f g0[16], g1[16], g2[16];
  int j0r = l, j1r = 64 + l, j2r = 128 + l;
  ld_g(g0, gb, j0r); ld_g(g1, gb, j1r); ld_g(g2, gb, j2r);

  int jlo = 0;
  int jhi = (ws < len - 1) ? ws : (len - 1);

  float m_run = -3.0e38f;   // deferred running max
  int t = 0;
  for (; t < len; ++t) {
    int qb = jlo >> 2;                       // 4-row chunk index
    // ---- Ptg reads (VMEM pipe; overlap the DS/w-stream below) ----
    float4 rp[17];
    {
      const float* pr = pvK + (size_t)(qb + h) * PTK;
      #pragma unroll
      for (int i = 0; i < 17; ++i) rp[i] = *(const float4*)(pr + (size_t)(2 * i) * PTK);
    }
    __builtin_amdgcn_sched_barrier(0);
    // ---- scores from register slots (packed f32 FMA, q uniform) ----
    float s0 = score_pk(g0, qp);
    float s1 = score_pk(g1, qp);
    float s2 = score_pk(g2, qp);
    bool v0 = (j0r >= jlo) & (j0r <= jhi);
    bool v1 = (j1r >= jlo) & (j1r <= jhi);
    bool v2 = (j2r >= jlo) & (j2r <= jhi);
    const float NEG = -3.0e38f;
    float mx0 = fmaxf(fmaxf(v0 ? s0 : NEG, v1 ? s1 : NEG), v2 ? s2 : NEG);
    // speculative exp with running max; rare fixup when band violated
    float mx = m_run;
    float e0 = v0 ? __expf(s0 - mx) : 0.f;
    float e1 = v1 ? __expf(s1 - mx) : 0.f;
    float e2 = v2 ? __expf(s2 - mx) : 0.f;
    if (!(__all(mx0 <= m_run + 8.0f) && __any(mx0 >= m_run - 20.0f))) {
      mx = red_max64(mx0);
      m_run = mx;
      e0 = v0 ? __expf(s0 - mx) : 0.f;
      e1 = v1 ? __expf(s1 - mx) : 0.f;
      e2 = v2 ? __expf(s2 - mx) : 0.f;
    }
    // unnormalized e scatter into LDS (row j%64 == lane: conflict-free)
    if (l == 0 && jlo > 0) w_lds[jlo - 1] = 0.f;  // evict stale window entry
    if (v0) w_lds[j0r] = e0;
    if (v1) w_lds[j1r] = e1;
    if (v2) w_lds[j2r] = e2;
    // sum reduce + rcp + weight stores: cover for the w-read drain below
    float sm = red_sum64(e0 + e1 + e2);
    float invS = __builtin_amdgcn_rcpf(sm);
    float* wrow = wb + (size_t)t * TT;
    if (v0) wrow[j0r] = e0 * invS;
    if (v1) wrow[j1r] = e1 * invS;
    if (v2) wrow[j2r] = e2 * invS;
    // ---- PV: w from LDS (in-order after e-writes), P from rp registers ----
    v2f pA = (v2f){0.f, 0.f}, pB = (v2f){0.f, 0.f};
    v2f pC = (v2f){0.f, 0.f}, pD = (v2f){0.f, 0.f};
    {
      const float* wr = w_lds + ((qb + h) << 2);
      #pragma unroll
      for (int i = 0; i < 17; i += 2) {
        float4 wv = *(const float4*)(wr + (i << 3));
        pA = pk_fma((v2f){wv.x, wv.y}, (v2f){rp[i].x, rp[i].y}, pA);
        pB = pk_fma((v2f){wv.z, wv.w}, (v2f){rp[i].z, rp[i].w}, pB);
      }
      #pragma unroll
      for (int i = 1; i < 17; i += 2) {
        float4 wv = *(const float4*)(wr + (i << 3));
        pC = pk_fma((v2f){wv.x, wv.y}, (v2f){rp[i].x, rp[i].y}, pC);
        pD = pk_fma((v2f){wv.z, wv.w}, (v2f){rp[i].z, rp[i].w}, pD);
      }
    }
    v2f ps = (pA + pC) + (pB + pD);
    float tot = ps.x + ps.y;
    // cross-half combine: pure-VALU permlane32_swap (proven R8/R10/R12)
    float tc = tot;
    asm("v_permlane32_swap_b32 %0, %1" : "+v"(tot), "+v"(tc));
    float comb = tot + tc;
    float nq = comb * invS + boutk;
    if (h == 0 && k < OD) outb[(size_t)t * OD + k] = nq;
    // broadcast new query into packed uniform pairs (on-chain)
    #pragma unroll
    for (int kk = 0; kk < 14; ++kk) {
      float lo = __int_as_float(__builtin_amdgcn_readlane(__float_as_int(nq), 2*kk));
      float hi = __int_as_float(__builtin_amdgcn_readlane(__float_as_int(nq), 2*kk+1));
      qp[kk] = (v2f){lo, hi};
    }
    qp[14] = (v2f){__int_as_float(__builtin_amdgcn_readlane(__float_as_int(nq), 28)), 1.0f};
    // rolling refill, prefetch distance 2 (fully off-chain)
    int jnew = t + 2 + ws;
    if (jnew >= 192 && jnew < TT) {
      int sl = (jnew >> 6) % 3;
      int ln = jnew & 63;
      if (sl == 0)      { if (l == ln) { ld_g(g0, gb, jnew); j0r = jnew; } }
      else if (sl == 1) { if (l == ln) { ld_g(g1, gb, jnew); j1r = jnew; } }
      else              { if (l == ln) { ld_g(g2, gb, jnew); j2r = jnew; } }
    }
    // advance window
    jlo = (t + 1) - ws; if (jlo < 0) jlo = 0;
    jhi = (t + 1) + ws; if (jhi > len - 1) jhi = len - 1;
  }
  // dead tail: outputs = b_out, weights stay zero
  for (; t < TT; ++t)
    if (l < OD) outb[(size_t)t * OD + l] = boutk;
}

extern "C" void kernel_launch(void* const* d_in, const int* in_sizes, int n_in,
                              void* d_out, int out_size, void* d_ws, size_t ws_size,
                              hipStream_t stream) {
  const float* x     = (const float*)d_in[0];
  const int*   lens  = (const int*)d_in[1];
  const float* W_in  = (const float*)d_in[2];
  const float* b_in  = (const float*)d_in[3];
  const float* W_q   = (const float*)d_in[4];
  const float* b_q   = (const float*)d_in[5];
  const float* W_out = (const float*)d_in[6];
  const float* b_out = (const float*)d_in[7];
  const int*   wsp   = (const int*)d_in[8];
  float* out = (float*)d_out;

  float* Wt  = (float*)d_ws;                      // [2049][64]
  float* GPC = Wt + (size_t)(IND + 1) * WCOLS;    // [B*T][32]
  float* Ptg = GPC + (size_t)BB * TT * GC;        // [B][160][29][4]

  float* outputs = out;
  float* weights = out + (size_t)BB * TT * OD;

  // transform folds weights AND zeroes weights-out + Ptg (overlapped stores);
  // outputs region is fully rewritten by k_scan each call.
  k_transform<<<IND + 1, 64, 0, stream>>>(W_in, b_in, W_q, b_q, W_out, Wt,
                                          weights, BB * TT * TT, Ptg, BB * PTB);
  k_gemm<<<(BB * TT) / 64, 256, 0, stream>>>(x, Wt, GPC, Ptg);
  k_scan<<<BB, 64, 0, stream>>>(GPC, Ptg, lens, b_out, wsp, outputs, weights);
}